// Round 6
// baseline (167.920 us; speedup 1.0000x reference)
//
#include <hip/hip_runtime.h>
#include <hip/hip_fp16.h>

// RoIAlign-3D: x[2,256,16,64,64] f32, rois[128,5] -> out[128,256,16,7,7] f32
// R6: ROI-persistent waves. Pre-kernel sorts ROIs by image into 128-slot lists
// (sentinel -1) and builds per-(slot,ph|pw) factored 3-tap meta (fp16 x-weights,
// byte offsets). Main: block = one c, 8 waves, 32 ROI-slots, loops 8 t-pairs;
// two planes LDS-interleaved as v2f [65][66] (pitch 528B: 16B-aligned windows,
// odd row-skew for banks). Lane o<49 = one output of one ROI; per-ROI meta
// hoisted to registers for 4 slots -> inner loop = 6 ds_read_b128 + FMA + 2 st.

typedef float v2f __attribute__((ext_vector_type(2)));
typedef float v4f __attribute__((ext_vector_type(4)));

#define ROWB 528   // 66 v2f * 8B

__global__ __launch_bounds__(256) void pooler_pre(const float* __restrict__ rois,
                                                  int* __restrict__ list,
                                                  uint4* __restrict__ meta) {
    __shared__ int simg[128];
    __shared__ int sslot[256];
    const int tid = threadIdx.x;
    if (tid < 128) simg[tid] = (int)rois[5 * tid];
    __syncthreads();
    if (tid == 0) {
        int c0 = 0, c1 = 0;
        for (int j = 0; j < 128; ++j) {
            if (simg[j] == 0) sslot[c0++] = j;
            else              sslot[128 + c1++] = j;
        }
        for (int j = c0; j < 128; ++j) sslot[j] = -1;
        for (int j = c1; j < 128; ++j) sslot[128 + j] = -1;
    }
    __syncthreads();
    const int k = sslot[tid];
    list[tid] = k;
    if (k < 0) {
        uint4 z = make_uint4(0, 0, 0, 0);
        for (int e = 0; e < 14; ++e) meta[tid * 14 + e] = z;
        return;
    }
    float x1 = rois[5*k+1]*0.25f, y1 = rois[5*k+2]*0.25f;
    float x2 = rois[5*k+3]*0.25f, y2 = rois[5*k+4]*0.25f;
    float bw = fmaxf(x2 - x1, 1.0f) * (1.0f / 14.0f);
    float bh = fmaxf(y2 - y1, 1.0f) * (1.0f / 14.0f);
    for (int i = 0; i < 7; ++i) {
        // ---- y: 2 samples -> 3-row weights (mask folded), f32
        float ys0 = fmaf((float)(2*i) + 0.5f, bh, y1);
        float ys1 = ys0 + bh;
        float my0 = (ys0 >= -1.0f && ys0 <= 64.0f) ? 1.0f : 0.0f;
        float my1 = (ys1 >= -1.0f && ys1 <= 64.0f) ? 1.0f : 0.0f;
        float yc0 = fminf(fmaxf(ys0, 0.0f), 63.0f);
        float yc1 = fminf(fmaxf(ys1, 0.0f), 63.0f);
        int y00 = min((int)yc0, 62), y01 = min((int)yc1, 62);
        float ly0 = yc0 - (float)y00, ly1 = yc1 - (float)y01;
        float h0 = (1.0f - ly0) * my0, l0 = ly0 * my0;
        float h1 = (1.0f - ly1) * my1, l1 = ly1 * my1;
        bool dy = (y01 != y00);
        float yw0 = h0 + (dy ? 0.0f : h1);
        float yw1 = l0 + (dy ? h1 : l1);
        float yw2 = dy ? l1 : 0.0f;   // row y00+2 weight; ==0 when y00==62 (pad row ok)
        uint4 e;
        e.x = __float_as_uint(yw0);
        e.y = __float_as_uint(yw1);
        e.z = __float_as_uint(yw2);
        e.w = (unsigned)(y00 * ROWB);
        meta[tid * 14 + i] = e;
        // ---- x: 2 samples -> 4-col even-aligned window (mask, 1/4, shift folded)
        float xs0 = fmaf((float)(2*i) + 0.5f, bw, x1);
        float xs1 = xs0 + bw;
        float mx0 = (xs0 >= -1.0f && xs0 <= 64.0f) ? 0.25f : 0.0f;
        float mx1 = (xs1 >= -1.0f && xs1 <= 64.0f) ? 0.25f : 0.0f;
        float xc0 = fminf(fmaxf(xs0, 0.0f), 63.0f);
        float xc1 = fminf(fmaxf(xs1, 0.0f), 63.0f);
        int x00 = min((int)xc0, 62), x01 = min((int)xc1, 62);
        float lx0 = xc0 - (float)x00, lx1 = xc1 - (float)x01;
        float a0 = (1.0f - lx0) * mx0, b0 = lx0 * mx0;
        float a1 = (1.0f - lx1) * mx1, b1 = lx1 * mx1;
        bool dx = (x01 != x00);
        float xw0 = a0 + (dx ? 0.0f : a1);
        float xw1 = b0 + (dx ? a1 : b1);
        float xw2 = dx ? b1 : 0.0f;
        bool odd = (x00 & 1);
        float w0 = odd ? 0.0f : xw0;
        float w1 = odd ? xw0 : xw1;
        float w2 = odd ? xw1 : xw2;
        float w3 = odd ? xw2 : 0.0f;  // col base+3; cols 64/65 are zero pads
        uint4 f;
        f.x = __builtin_bit_cast(unsigned, __halves2half2(__float2half(w0), __float2half(w1)));
        f.y = __builtin_bit_cast(unsigned, __halves2half2(__float2half(w2), __float2half(w3)));
        f.z = (unsigned)((x00 & ~1) * 8);
        f.w = 0;
        meta[tid * 14 + 7 + i] = f;
    }
}

__global__ __launch_bounds__(512, 6) void pooler_main(const float* __restrict__ x,
                                                      const int* __restrict__ list,
                                                      const uint4* __restrict__ meta,
                                                      float* __restrict__ out) {
    __shared__ __align__(16) float plane2[65 * 66 * 2];  // v2f[65][66]: 2 t-planes interleaved
    __shared__ __align__(16) uint4 tab[32 * 14];

    const int tid = threadIdx.x;
    const int bid = blockIdx.x;
    const int c   = bid & 255;
    const int lb  = (bid >> 8) & 3;
    const int img = bid >> 10;
    const int sbase = img * 128 + lb * 32;
    if (list[sbase] < 0) return;       // fully-sentinel block: exit before barriers

    if (tid < 448) tab[tid] = meta[sbase * 14 + tid];
    if (tid < 98) {                    // zero pads: cols 64,65 all rows; pad row 64
        v4f z = {0.f, 0.f, 0.f, 0.f};
        if (tid < 65) *(v4f*)&plane2[(tid * 66 + 64) * 2] = z;
        else          *(v4f*)&plane2[(64 * 66 + (tid - 65) * 2) * 2] = z;
    }

    const int lane = tid & 63, wave = tid >> 6;
    const int o  = lane;
    const int oc = o < 49 ? o : 0;
    const int ph = oc / 7, pw = oc - ph * 7;

    __syncthreads();                   // tab + pads ready

    // Hoist 4 ROI-slots of meta into registers (invariant over the t-pair loop).
    float yv0[4], yv1[4], yv2[4], w0[4], w1[4], w2[4], w3[4];
    int poff[4];
    unsigned obase[4];                 // k*200704 + c*784 + o, or sign bit = skip
    #pragma unroll
    for (int j = 0; j < 4; ++j) {
        int s = wave * 4 + j;
        int k = list[sbase + s];
        uint4 ye = tab[s * 14 + ph];
        uint4 xe = tab[s * 14 + 7 + pw];
        yv0[j] = __uint_as_float(ye.x);
        yv1[j] = __uint_as_float(ye.y);
        yv2[j] = __uint_as_float(ye.z);
        float2 ab = __half22float2(__builtin_bit_cast(__half2, xe.x));
        float2 cd = __half22float2(__builtin_bit_cast(__half2, xe.y));
        w0[j] = ab.x; w1[j] = ab.y; w2[j] = cd.x; w3[j] = cd.y;
        poff[j] = (int)(ye.w + xe.z);
        obase[j] = k < 0 ? 0x80000000u
                         : (unsigned)k * 200704u + (unsigned)(c * 16) * 49u + (unsigned)o;
    }

    // Staging map: thread -> (row y, 8-col group xq); 2 float4 per plane.
    const int y = tid >> 3, xq = tid & 7;
    const float4* gb = (const float4*)(x + ((size_t)(img * 256 + c) * 16) * 4096);
    const int goff = y * 16 + xq * 2;
    float4 g0, g1, g2, g3;
    g0 = gb[goff]; g1 = gb[goff + 1]; g2 = gb[1024 + goff]; g3 = gb[1024 + goff + 1];

    for (int i = 0; i < 8; ++i) {
        __syncthreads();               // previous iteration done reading LDS
        {
            v4f* d = (v4f*)&plane2[(y * 66 + xq * 8) * 2];
            d[0] = v4f{g0.x, g2.x, g0.y, g2.y};
            d[1] = v4f{g0.z, g2.z, g0.w, g2.w};
            d[2] = v4f{g1.x, g3.x, g1.y, g3.y};
            d[3] = v4f{g1.z, g3.z, g1.w, g3.w};
        }
        __syncthreads();
        if (i < 7) {                   // T14: issue next pair's loads under compute
            const float4* p0 = gb + (2 * i + 2) * 1024 + goff;
            const float4* p1 = gb + (2 * i + 3) * 1024 + goff;
            g0 = p0[0]; g1 = p0[1]; g2 = p1[0]; g3 = p1[1];
        }
        if (o < 49) {
            #pragma unroll
            for (int j = 0; j < 4; ++j) {
                if ((int)obase[j] < 0) continue;
                const char* pr = (const char*)plane2 + poff[j];
                v4f q0 = *(const v4f*)pr,              q1 = *(const v4f*)(pr + 16);
                v4f r0 = *(const v4f*)(pr + ROWB),     r1 = *(const v4f*)(pr + ROWB + 16);
                v4f s0 = *(const v4f*)(pr + 2 * ROWB), s1 = *(const v4f*)(pr + 2 * ROWB + 16);
                v2f t0 = v2f{q0.x, q0.y} * w0[j] + v2f{q0.z, q0.w} * w1[j]
                       + v2f{q1.x, q1.y} * w2[j] + v2f{q1.z, q1.w} * w3[j];
                v2f t1 = v2f{r0.x, r0.y} * w0[j] + v2f{r0.z, r0.w} * w1[j]
                       + v2f{r1.x, r1.y} * w2[j] + v2f{r1.z, r1.w} * w3[j];
                v2f t2 = v2f{s0.x, s0.y} * w0[j] + v2f{s0.z, s0.w} * w1[j]
                       + v2f{s1.x, s1.y} * w2[j] + v2f{s1.z, s1.w} * w3[j];
                v2f acc = t0 * yv0[j] + t1 * yv1[j] + t2 * yv2[j];
                float* po = out + obase[j] + (unsigned)(2 * i) * 49u;
                po[0]  = acc.x;
                po[49] = acc.y;
            }
        }
    }
}

extern "C" void kernel_launch(void* const* d_in, const int* in_sizes, int n_in,
                              void* d_out, int out_size, void* d_ws, size_t ws_size,
                              hipStream_t stream) {
    const float* x    = (const float*)d_in[0];
    const float* rois = (const float*)d_in[1];
    float* out = (float*)d_out;
    int*   list = (int*)d_ws;
    uint4* meta = (uint4*)((char*)d_ws + 1024);
    pooler_pre<<<1, 256, 0, stream>>>(rois, list, meta);
    pooler_main<<<2048, 512, 0, stream>>>(x, list, meta, out);
}

// Round 7
// 76.116 us; speedup vs baseline: 2.2061x; 2.2061x over previous
//
#include <hip/hip_runtime.h>
#include <hip/hip_fp16.h>

// RoIAlign-3D: x[2,256,16,64,64] f32, rois[128,5] -> out[128,256,16,7,7] f32
// R7: R6 structure, re-fetch bug fixed. Block = (img, c, t-half): stages its
// 8 planes exactly once as 4 reg-prefetched t-pairs (v2f-interleaved LDS,
// [65][66] v2f, pitch 528B -> all window reads 16B-aligned b128). Wave = 64
// lanes, lane o<49 = one (ph,pw) output; wave loops ROI-slots wave+8j
// (j<16, covers up to 128 ROIs/image, sentinel break). Meta (factored 3-tap
// weights, byte offsets) built by pre-kernel, gathered from L1 per task.

typedef float v2f __attribute__((ext_vector_type(2)));
typedef float v4f __attribute__((ext_vector_type(4)));

#define ROWB 528   // 66 v2f * 8B; multiple of 16 -> even-col windows b128-aligned

__global__ __launch_bounds__(256) void pooler_pre(const float* __restrict__ rois,
                                                  int* __restrict__ list,
                                                  uint4* __restrict__ meta) {
    __shared__ int simg[128];
    __shared__ int sslot[256];
    const int tid = threadIdx.x;
    if (tid < 128) simg[tid] = (int)rois[5 * tid];
    __syncthreads();
    if (tid == 0) {
        int c0 = 0, c1 = 0;
        for (int j = 0; j < 128; ++j) {
            if (simg[j] == 0) sslot[c0++] = j;
            else              sslot[128 + c1++] = j;
        }
        for (int j = c0; j < 128; ++j) sslot[j] = -1;
        for (int j = c1; j < 128; ++j) sslot[128 + j] = -1;
    }
    __syncthreads();
    const int k = sslot[tid];
    list[tid] = k;
    if (k < 0) return;                 // meta never read for sentinel slots
    float x1 = rois[5*k+1]*0.25f, y1 = rois[5*k+2]*0.25f;
    float x2 = rois[5*k+3]*0.25f, y2 = rois[5*k+4]*0.25f;
    float bw = fmaxf(x2 - x1, 1.0f) * (1.0f / 14.0f);
    float bh = fmaxf(y2 - y1, 1.0f) * (1.0f / 14.0f);
    for (int i = 0; i < 7; ++i) {
        // ---- y: 2 samples -> 3-row weights (mask folded), f32
        float ys0 = fmaf((float)(2*i) + 0.5f, bh, y1);
        float ys1 = ys0 + bh;
        float my0 = (ys0 >= -1.0f && ys0 <= 64.0f) ? 1.0f : 0.0f;
        float my1 = (ys1 >= -1.0f && ys1 <= 64.0f) ? 1.0f : 0.0f;
        float yc0 = fminf(fmaxf(ys0, 0.0f), 63.0f);
        float yc1 = fminf(fmaxf(ys1, 0.0f), 63.0f);
        int y00 = min((int)yc0, 62), y01 = min((int)yc1, 62);
        float ly0 = yc0 - (float)y00, ly1 = yc1 - (float)y01;
        float h0 = (1.0f - ly0) * my0, l0 = ly0 * my0;
        float h1 = (1.0f - ly1) * my1, l1 = ly1 * my1;
        bool dy = (y01 != y00);
        float yw0 = h0 + (dy ? 0.0f : h1);
        float yw1 = l0 + (dy ? h1 : l1);
        float yw2 = dy ? l1 : 0.0f;    // row y00+2; ==0 when y00==62 (pad row safe)
        uint4 e;
        e.x = __float_as_uint(yw0);
        e.y = __float_as_uint(yw1);
        e.z = __float_as_uint(yw2);
        e.w = (unsigned)(y00 * ROWB);
        meta[tid * 14 + i] = e;
        // ---- x: 2 samples -> 4-col even-aligned window (mask, 1/4, shift folded)
        float xs0 = fmaf((float)(2*i) + 0.5f, bw, x1);
        float xs1 = xs0 + bw;
        float mx0 = (xs0 >= -1.0f && xs0 <= 64.0f) ? 0.25f : 0.0f;
        float mx1 = (xs1 >= -1.0f && xs1 <= 64.0f) ? 0.25f : 0.0f;
        float xc0 = fminf(fmaxf(xs0, 0.0f), 63.0f);
        float xc1 = fminf(fmaxf(xs1, 0.0f), 63.0f);
        int x00 = min((int)xc0, 62), x01 = min((int)xc1, 62);
        float lx0 = xc0 - (float)x00, lx1 = xc1 - (float)x01;
        float a0 = (1.0f - lx0) * mx0, b0 = lx0 * mx0;
        float a1 = (1.0f - lx1) * mx1, b1 = lx1 * mx1;
        bool dx = (x01 != x00);
        float xw0 = a0 + (dx ? 0.0f : a1);
        float xw1 = b0 + (dx ? a1 : b1);
        float xw2 = dx ? b1 : 0.0f;
        bool odd = (x00 & 1);
        float w0 = odd ? 0.0f : xw0;
        float w1 = odd ? xw0 : xw1;
        float w2 = odd ? xw1 : xw2;
        float w3 = odd ? xw2 : 0.0f;   // col base+3; cols 64/65 zero pads
        uint4 f;
        f.x = __builtin_bit_cast(unsigned, __halves2half2(__float2half(w0), __float2half(w1)));
        f.y = __builtin_bit_cast(unsigned, __halves2half2(__float2half(w2), __float2half(w3)));
        f.z = (unsigned)((x00 & ~1) * 8);
        f.w = 0;
        meta[tid * 14 + 7 + i] = f;
    }
}

__global__ __launch_bounds__(512, 4) void pooler_main(const float* __restrict__ x,
                                                      const int* __restrict__ list,
                                                      const uint4* __restrict__ meta,
                                                      float* __restrict__ out) {
    __shared__ __align__(16) float plane2[65 * 66 * 2];  // v2f[65][66]: t-pair interleaved

    const int tid = threadIdx.x;
    const int bid = blockIdx.x;
    const int th  = bid & 1;
    const int c   = (bid >> 1) & 255;
    const int img = bid >> 9;
    const int sbase = img << 7;

    const int lane = tid & 63, wave = tid >> 6;
    const int o  = lane;
    const int oc = o < 49 ? o : 48;
    const int ph = oc / 7, pw = oc - ph * 7;

    // Zero pads once: cols 64,65 rows 0..64; pad row 64 cols 0..63.
    if (tid < 97) {
        v4f z = {0.f, 0.f, 0.f, 0.f};
        if (tid < 65) *(v4f*)&plane2[(tid * 66 + 64) * 2] = z;
        else          *(v4f*)&plane2[(64 * 66 + (tid - 65) * 2) * 2] = z;
    }

    // Staging map: thread -> (row y, 8-col group xq); 2 float4 per plane.
    const int y = tid >> 3, xq = tid & 7;
    const float4* gb = (const float4*)(x + ((size_t)((img << 8) + c) << 16));
    const int goff = y * 16 + xq * 2;
    const int tbase = th * 8;
    float4 g0, g1, g2, g3;
    {
        const float4* p0 = gb + (size_t)tbase * 1024 + goff;
        const float4* p1 = gb + (size_t)(tbase + 1) * 1024 + goff;
        g0 = p0[0]; g1 = p0[1]; g2 = p1[0]; g3 = p1[1];
    }

    for (int i = 0; i < 4; ++i) {
        __syncthreads();               // previous iteration done reading LDS
        {
            v4f* d = (v4f*)&plane2[(y * 66 + xq * 8) * 2];
            d[0] = v4f{g0.x, g2.x, g0.y, g2.y};
            d[1] = v4f{g0.z, g2.z, g0.w, g2.w};
            d[2] = v4f{g1.x, g3.x, g1.y, g3.y};
            d[3] = v4f{g1.z, g3.z, g1.w, g3.w};
        }
        __syncthreads();
        if (i < 3) {                   // T14: next pair's loads land under compute
            const float4* p0 = gb + (size_t)(tbase + 2 * i + 2) * 1024 + goff;
            const float4* p1 = gb + (size_t)(tbase + 2 * i + 3) * 1024 + goff;
            g0 = p0[0]; g1 = p0[1]; g2 = p1[0]; g3 = p1[1];
        }
        const int t = tbase + 2 * i;
        if (o < 49) {
            for (int j = 0; j < 16; ++j) {
                int s = wave + (j << 3);           // wave-uniform slot
                int k = list[sbase + s];
                if (k < 0) break;                  // sorted: rest are sentinels too
                const uint4* mrow = meta + (size_t)(sbase + s) * 14;
                uint4 ye = mrow[ph];
                uint4 xe = mrow[7 + pw];
                float yv0 = __uint_as_float(ye.x);
                float yv1 = __uint_as_float(ye.y);
                float yv2 = __uint_as_float(ye.z);
                float2 ab = __half22float2(__builtin_bit_cast(__half2, xe.x));
                float2 cd = __half22float2(__builtin_bit_cast(__half2, xe.y));
                const char* pr = (const char*)plane2 + (ye.w + xe.z);
                v4f q0 = *(const v4f*)pr,              q1 = *(const v4f*)(pr + 16);
                v4f r0 = *(const v4f*)(pr + ROWB),     r1 = *(const v4f*)(pr + ROWB + 16);
                v4f s0 = *(const v4f*)(pr + 2*ROWB),   s1 = *(const v4f*)(pr + 2*ROWB + 16);
                v2f t0 = v2f{q0.x, q0.y} * ab.x + v2f{q0.z, q0.w} * ab.y
                       + v2f{q1.x, q1.y} * cd.x + v2f{q1.z, q1.w} * cd.y;
                v2f t1 = v2f{r0.x, r0.y} * ab.x + v2f{r0.z, r0.w} * ab.y
                       + v2f{r1.x, r1.y} * cd.x + v2f{r1.z, r1.w} * cd.y;
                v2f t2 = v2f{s0.x, s0.y} * ab.x + v2f{s0.z, s0.w} * ab.y
                       + v2f{s1.x, s1.y} * cd.x + v2f{s1.z, s1.w} * cd.y;
                v2f acc = t0 * yv0 + t1 * yv1 + t2 * yv2;
                float* po = out + (size_t)k * 200704 + (size_t)((c << 4) + t) * 49 + o;
                po[0]  = acc.x;
                po[49] = acc.y;
            }
        }
    }
}

extern "C" void kernel_launch(void* const* d_in, const int* in_sizes, int n_in,
                              void* d_out, int out_size, void* d_ws, size_t ws_size,
                              hipStream_t stream) {
    const float* x    = (const float*)d_in[0];
    const float* rois = (const float*)d_in[1];
    float* out = (float*)d_out;
    int*   list = (int*)d_ws;
    uint4* meta = (uint4*)((char*)d_ws + 1024);
    pooler_pre<<<1, 256, 0, stream>>>(rois, list, meta);
    pooler_main<<<1024, 512, 0, stream>>>(x, list, meta, out);
}

// Round 8
// 63.211 us; speedup vs baseline: 2.6565x; 1.2042x over previous
//
#include <hip/hip_runtime.h>

// RoIAlign-3D: x[2,256,16,64,64] f32, rois[128,5] -> out[128,256,16,7,7] f32
// R8: v4f 4-plane-interleaved LDS, one 16B chunk per texel. 3x3 window =
// 9 aligned ds_read_b128 per 4 outputs (2.25/out). Pitch 65 chunks/row +
// additive row-pair col-shift (breaks even-stride bank parity; staging writes
// stay linear/conflict-free). Clamp+shift boundary (no pads). Padded per-image
// slot lists (dup-k, benign identical rewrites) -> uniform j trip count, no
// break, explicit next-j meta prefetch. All-f32 weights.

typedef float v4f __attribute__((ext_vector_type(4)));

#define PITCHB 1040   // 65 chunks * 16B per row

__global__ __launch_bounds__(256) void pooler_pre(const float* __restrict__ rois,
                                                  int* __restrict__ list,
                                                  int* __restrict__ jt,
                                                  uint4* __restrict__ meta) {
    __shared__ int simg[128];
    __shared__ int sorted[256];
    __shared__ int scnt[2];
    const int tid = threadIdx.x;
    if (tid < 128) simg[tid] = (int)rois[5 * tid];
    __syncthreads();
    if (tid == 0) {
        int c0 = 0, c1 = 0;
        for (int j = 0; j < 128; ++j) {
            if (simg[j] == 0) sorted[c0++] = j;
            else              sorted[128 + c1++] = j;
        }
        scnt[0] = c0; scnt[1] = c1;
        jt[0] = (c0 + 7) >> 3;
        jt[1] = (c1 + 7) >> 3;
    }
    __syncthreads();
    const int img = tid >> 7, idx = tid & 127;
    const int cnt = scnt[img];
    int k = 0;
    if (cnt > 0) k = (idx < cnt) ? sorted[(img << 7) + idx] : sorted[img << 7];
    list[tid] = k;   // pad slots duplicate the image's first ROI (identical rewrites)

    float x1 = rois[5*k+1]*0.25f, y1 = rois[5*k+2]*0.25f;
    float x2 = rois[5*k+3]*0.25f, y2 = rois[5*k+4]*0.25f;
    float bw = fmaxf(x2 - x1, 1.0f) * (1.0f / 14.0f);
    float bh = fmaxf(y2 - y1, 1.0f) * (1.0f / 14.0f);
    for (int i = 0; i < 7; ++i) {
        {   // ---- y: 2 samples -> 3-row weights (mask folded); clamp+shift
            float s0 = fmaf((float)(2*i) + 0.5f, bh, y1), s1 = s0 + bh;
            float m0 = (s0 >= -1.f && s0 <= 64.f) ? 1.f : 0.f;
            float m1 = (s1 >= -1.f && s1 <= 64.f) ? 1.f : 0.f;
            float c0 = fminf(fmaxf(s0, 0.f), 63.f), c1 = fminf(fmaxf(s1, 0.f), 63.f);
            int i0 = min((int)c0, 62), i1 = min((int)c1, 62);
            float l0 = c0 - (float)i0, l1 = c1 - (float)i1;
            float h0 = (1.f - l0) * m0, L0 = l0 * m0;
            float h1 = (1.f - l1) * m1, L1 = l1 * m1;
            bool d = (i1 != i0);
            float w0 = h0 + (d ? 0.f : h1);
            float w1 = L0 + (d ? h1 : L1);
            float w2 = d ? L1 : 0.f;            // ==0 when i0==62
            int b = i0;
            if (i0 > 61) { b = 61; w2 = w1; w1 = w0; w0 = 0.f; }
            uint4 e;
            e.x = __float_as_uint(w0); e.y = __float_as_uint(w1);
            e.z = __float_as_uint(w2); e.w = (unsigned)b;
            meta[tid * 14 + i] = e;
        }
        {   // ---- x: same, 1/4 sample-mean folded
            float s0 = fmaf((float)(2*i) + 0.5f, bw, x1), s1 = s0 + bw;
            float m0 = (s0 >= -1.f && s0 <= 64.f) ? 0.25f : 0.f;
            float m1 = (s1 >= -1.f && s1 <= 64.f) ? 0.25f : 0.f;
            float c0 = fminf(fmaxf(s0, 0.f), 63.f), c1 = fminf(fmaxf(s1, 0.f), 63.f);
            int i0 = min((int)c0, 62), i1 = min((int)c1, 62);
            float l0 = c0 - (float)i0, l1 = c1 - (float)i1;
            float h0 = (1.f - l0) * m0, L0 = l0 * m0;
            float h1 = (1.f - l1) * m1, L1 = l1 * m1;
            bool d = (i1 != i0);
            float w0 = h0 + (d ? 0.f : h1);
            float w1 = L0 + (d ? h1 : L1);
            float w2 = d ? L1 : 0.f;
            int b = i0;
            if (i0 > 61) { b = 61; w2 = w1; w1 = w0; w0 = 0.f; }
            uint4 e;
            e.x = __float_as_uint(w0); e.y = __float_as_uint(w1);
            e.z = __float_as_uint(w2); e.w = (unsigned)b;
            meta[tid * 14 + 7 + i] = e;
        }
    }
}

__global__ __launch_bounds__(512, 4) void pooler_main(const float* __restrict__ x,
                                                      const int* __restrict__ list,
                                                      const int* __restrict__ jt,
                                                      const uint4* __restrict__ meta,
                                                      float* __restrict__ out) {
    __shared__ __align__(16) char lds[64 * PITCHB];   // 66,560 B -> 2 blocks/CU

    const int tid = threadIdx.x;
    const int bid = blockIdx.x;
    const int th  = bid & 1;
    const int c   = (bid >> 1) & 255;
    const int img = bid >> 9;
    const int sbase = img << 7;
    const int jtn = jt[img];

    const int lane = tid & 63, wave = tid >> 6;
    const int o  = lane;
    const int oc = o < 49 ? o : 48;
    const int ph = oc / 7, pw = oc - ph * 7;

    // (img,c) base + th*8 planes
    const float* gbase = x + (((size_t)((img << 8) + c)) << 16) + ((size_t)th << 15);

    float buf[32];
    #pragma unroll
    for (int m = 0; m < 8; ++m) {          // prologue: round-0 planes 0..3
        int n = tid + (m << 9);
        #pragma unroll
        for (int t = 0; t < 4; ++t) buf[m * 4 + t] = gbase[t * 4096 + n];
    }

    for (int i = 0; i < 2; ++i) {
        __syncthreads();                   // previous round done reading LDS
        #pragma unroll
        for (int m = 0; m < 8; ++m) {      // linear conflict-free b128 writes
            int n = tid + (m << 9);
            int y = n >> 6, xx = n & 63;
            *(v4f*)(lds + y * PITCHB + ((xx + ((y >> 1) & 1)) << 4)) =
                v4f{buf[m*4], buf[m*4+1], buf[m*4+2], buf[m*4+3]};
        }
        __syncthreads();
        if (i == 0) {                      // T14: round-1 loads land under compute
            #pragma unroll
            for (int m = 0; m < 8; ++m) {
                int n = tid + (m << 9);
                #pragma unroll
                for (int t = 0; t < 4; ++t) buf[m*4+t] = gbase[16384 + t * 4096 + n];
            }
        }
        if (jtn > 0) {
            const int tb = (th << 3) + (i << 2);
            int s0 = sbase + wave;
            int k0 = list[s0];
            uint4 ye0 = meta[s0 * 14 + ph];
            uint4 xe0 = meta[s0 * 14 + 7 + pw];
            for (int j = 0; j < jtn; ++j) {
                int sn = sbase + wave + (min(j + 1, jtn - 1) << 3);
                int k1 = list[sn];                      // prefetch next
                uint4 ye1 = meta[sn * 14 + ph];
                uint4 xe1 = meta[sn * 14 + 7 + pw];

                float yw0 = __uint_as_float(ye0.x);
                float yw1 = __uint_as_float(ye0.y);
                float yw2 = __uint_as_float(ye0.z);
                float xw0 = __uint_as_float(xe0.x);
                float xw1 = __uint_as_float(xe0.y);
                float xw2 = __uint_as_float(xe0.z);
                int yb = (int)ye0.w, xb = (int)xe0.w;

                int r0 = yb, r1 = yb + 1, r2 = yb + 2;
                const char* p0 = lds + r0 * PITCHB + ((xb + ((r0 >> 1) & 1)) << 4);
                const char* p1 = lds + r1 * PITCHB + ((xb + ((r1 >> 1) & 1)) << 4);
                const char* p2 = lds + r2 * PITCHB + ((xb + ((r2 >> 1) & 1)) << 4);
                v4f a0 = *(const v4f*)p0, a1 = *(const v4f*)(p0+16), a2 = *(const v4f*)(p0+32);
                v4f b0 = *(const v4f*)p1, b1 = *(const v4f*)(p1+16), b2 = *(const v4f*)(p1+32);
                v4f c0 = *(const v4f*)p2, c1 = *(const v4f*)(p2+16), c2 = *(const v4f*)(p2+32);
                v4f t0 = a0 * xw0 + a1 * xw1 + a2 * xw2;
                v4f t1 = b0 * xw0 + b1 * xw1 + b2 * xw2;
                v4f t2 = c0 * xw0 + c1 * xw1 + c2 * xw2;
                v4f acc = t0 * yw0 + t1 * yw1 + t2 * yw2;

                if (o < 49) {
                    float* po = out + (size_t)k0 * 200704 + (size_t)((c << 4) + tb) * 49 + o;
                    po[0]   = acc.x;
                    po[49]  = acc.y;
                    po[98]  = acc.z;
                    po[147] = acc.w;
                }
                k0 = k1; ye0 = ye1; xe0 = xe1;
            }
        }
    }
}

extern "C" void kernel_launch(void* const* d_in, const int* in_sizes, int n_in,
                              void* d_out, int out_size, void* d_ws, size_t ws_size,
                              hipStream_t stream) {
    const float* x    = (const float*)d_in[0];
    const float* rois = (const float*)d_in[1];
    float* out = (float*)d_out;
    int*   list = (int*)d_ws;
    int*   jtp  = (int*)((char*)d_ws + 1024);
    uint4* meta = (uint4*)((char*)d_ws + 2048);
    pooler_pre<<<1, 256, 0, stream>>>(rois, list, jtp, meta);
    pooler_main<<<1024, 512, 0, stream>>>(x, list, jtp, meta, out);
}